// Round 6
// baseline (340.206 us; speedup 1.0000x reference)
//
#include <hip/hip_runtime.h>

typedef unsigned short u16;
typedef unsigned int u32;
typedef float f32x4 __attribute__((ext_vector_type(4)));
typedef __bf16 bf16x8 __attribute__((ext_vector_type(8)));

#define T_TOK 4096
#define HDIM 1024
#define IDIM 512
#define NEXP 32
#define KSEL 8
#define CAPE 2048
#define NROW (NEXP*CAPE + T_TOK)   // 69632 rows total (experts + shared)
#define MAXTILE 528                // 33 experts * 16 y-tiles max
#define NCVT2 132                  // 33 experts * 4 quarter-converts of w2

__device__ __forceinline__ u16 f32_to_bf16(float f) {
  u32 x = __float_as_uint(f);
  u32 r = (x + 0x7FFFu + ((x >> 16) & 1u)) >> 16;   // RNE; inputs finite
  return (u16)r;
}
__device__ __forceinline__ float bf16_to_f32(u16 u) {
  return __uint_as_float(((u32)u) << 16);
}

// ---------------- k_pre: gate (blocks 0..127) ∪ w13 interleave convert (blocks 128..2175) ----------------
__global__ __launch_bounds__(256) void k_pre(const float* __restrict__ x, const float* __restrict__ gw,
                                             const float* __restrict__ w13,
                                             const float* __restrict__ sw1, const float* __restrict__ sw3,
                                             int* __restrict__ idx, float* __restrict__ wts,
                                             u16* __restrict__ xb, u16* __restrict__ w13b,
                                             int* __restrict__ done) {
  const int tid = threadIdx.x;
  if (blockIdx.x >= 128) {
    const long n8 = (long)(NEXP + 1) * 1024 * 128;
    const long stride = (long)(2176 - 128) * 256;
    for (long j = (long)(blockIdx.x - 128) * 256 + tid; j < n8; j += stride) {
      int e   = (int)(j >> 17);
      int rem = (int)(j & 131071);
      int rowd = rem >> 7;
      int c8   = rem & 127;
      int c = rowd >> 4, cw = rowd & 15;
      int srow = (c >> 1) * 16 + cw;
      int sel = c & 1;
      const float* s;
      if (e < NEXP) s = w13 + (size_t)e * (2 * IDIM * HDIM) + (size_t)(sel * IDIM + srow) * HDIM + c8 * 8;
      else          s = (sel ? sw3 : sw1) + (size_t)srow * HDIM + c8 * 8;
      float4 a = reinterpret_cast<const float4*>(s)[0];
      float4 b = reinterpret_cast<const float4*>(s)[1];
      ushort4 lo, hi;
      lo.x=f32_to_bf16(a.x); lo.y=f32_to_bf16(a.y); lo.z=f32_to_bf16(a.z); lo.w=f32_to_bf16(a.w);
      hi.x=f32_to_bf16(b.x); hi.y=f32_to_bf16(b.y); hi.z=f32_to_bf16(b.z); hi.w=f32_to_bf16(b.w);
      u16* d = w13b + ((size_t)e * 1024 + rowd) * HDIM + c8 * 8;
      reinterpret_cast<ushort4*>(d)[0] = lo;
      reinterpret_cast<ushort4*>(d)[1] = hi;
    }
    return;
  }
  // ---- gate path ----
  __shared__ float xs[32][129];
  __shared__ float gs_[32][129];
  __shared__ double sc[32][32];
  const int t0 = blockIdx.x * 32;
  const int tl = tid & 31, g = tid >> 5;
  if (blockIdx.x == 0 && tid == 0) done[0] = 0;
  double acc0 = 0, acc1 = 0, acc2 = 0, acc3 = 0;
  for (int k0 = 0; k0 < HDIM; k0 += 128) {
#pragma unroll
    for (int q = 0; q < 4; ++q) {
      int f = tid + 256 * q;
      int row = f >> 5, c4 = (f & 31) * 4;
      float4 v = *reinterpret_cast<const float4*>(x + (long)(t0 + row) * HDIM + k0 + c4);
      xs[row][c4+0]=v.x; xs[row][c4+1]=v.y; xs[row][c4+2]=v.z; xs[row][c4+3]=v.w;
      ushort4 xv; xv.x=f32_to_bf16(v.x); xv.y=f32_to_bf16(v.y); xv.z=f32_to_bf16(v.z); xv.w=f32_to_bf16(v.w);
      *reinterpret_cast<ushort4*>(xb + (long)(t0 + row) * HDIM + k0 + c4) = xv;
      float4 w = *reinterpret_cast<const float4*>(gw + (long)row * HDIM + k0 + c4);
      gs_[row][c4+0]=w.x; gs_[row][c4+1]=w.y; gs_[row][c4+2]=w.z; gs_[row][c4+3]=w.w;
    }
    __syncthreads();
#pragma unroll 4
    for (int kk = 0; kk < 128; ++kk) {
      double xv = (double)xs[tl][kk];
      acc0 += xv * (double)gs_[g     ][kk];
      acc1 += xv * (double)gs_[g +  8][kk];
      acc2 += xv * (double)gs_[g + 16][kk];
      acc3 += xv * (double)gs_[g + 24][kk];
    }
    __syncthreads();
  }
  sc[tl][g     ] = acc0;
  sc[tl][g +  8] = acc1;
  sc[tl][g + 16] = acc2;
  sc[tl][g + 24] = acc3;
  __syncthreads();
  if (tid < 32) {
    int t = t0 + tid;
    double gsc[8];
#pragma unroll
    for (int gg = 0; gg < 8; ++gg) {
      double mx = sc[tid][4*gg];
#pragma unroll
      for (int j = 1; j < 4; ++j) mx = fmax(mx, sc[tid][4*gg + j]);
      gsc[gg] = mx;
    }
    unsigned gmask = 0;
    for (int it = 0; it < 4; ++it) {
      double best = -1e300; int bi = 0;
      for (int gg = 0; gg < 8; ++gg)
        if (!((gmask >> gg) & 1) && gsc[gg] > best) { best = gsc[gg]; bi = gg; }
      gmask |= 1u << bi;
    }
    unsigned emask = 0; int ei[KSEL]; double ew[KSEL]; double wsum = 0;
    for (int it = 0; it < KSEL; ++it) {
      double best = -1e300; int bi = 0;
      for (int e = 0; e < NEXP; ++e)
        if (((gmask >> (e >> 2)) & 1) && !((emask >> e) & 1)) {
          double v = sc[tid][e];
          if (v > best) { best = v; bi = e; }
        }
      emask |= 1u << bi; ei[it] = bi;
      double sg = 1.0 / (1.0 + exp(-best));
      ew[it] = sg; wsum += sg;
    }
    double s = 2.5 / (wsum + 1e-20);
    for (int k = 0; k < KSEL; ++k) { idx[t*KSEL + k] = ei[k]; wts[t*KSEL + k] = (float)(ew[k] * s); }
  }
}

// ---------------- capacity assignment (ballot-scan) + inline scheduler + queue reset ----------------
__global__ __launch_bounds__(1024) void k_assign(const int* __restrict__ idx,
                                                 int* __restrict__ etok, int* __restrict__ pos,
                                                 int* __restrict__ cnts,
                                                 int* __restrict__ list, int* __restrict__ tot,
                                                 int* __restrict__ done,
                                                 int* __restrict__ qhead, int* __restrict__ ready1,
                                                 int* __restrict__ cvt2) {
  const int e = blockIdx.x;
  const int tid = threadIdx.x;
  int base = 0;
  if (e == NEXP) {
    for (int t = tid; t < T_TOK; t += 1024) etok[NEXP*CAPE + t] = t;
    base = T_TOK;
  } else {
    __shared__ int wbase[17];
    const int wid = tid >> 6, lane = tid & 63;
    for (int c = 0; c < T_TOK / 1024; ++c) {
      int t = c * 1024 + tid;
      int found = -1;
#pragma unroll
      for (int k = 0; k < KSEL; ++k) if (idx[t*KSEL + k] == e) found = k;
      unsigned long long mask = __ballot(found >= 0);
      int myrank = __popcll(mask & ((1ull << lane) - 1ull));
      __syncthreads();
      if (lane == 0) wbase[wid] = __popcll(mask);
      __syncthreads();
      if (tid == 0) {
        int run = 0;
#pragma unroll
        for (int w = 0; w < 16; ++w) { int v = wbase[w]; wbase[w] = run; run += v; }
        wbase[16] = run;
      }
      __syncthreads();
      if (found >= 0) {
        int slot = base + wbase[wid] + myrank;
        pos[t*KSEL + found] = slot;
        if (slot < CAPE) etok[e*CAPE + slot] = t;
      }
      base += wbase[16];
      __syncthreads();
    }
    base = min(base, CAPE);
  }
  if (tid == 0) {
    cnts[e] = base;
    __threadfence();
    if (atomicAdd(done, 1) == NEXP) {          // last finisher: build work list + reset queue state
      __threadfence();
      int run = 0;
      for (int ee = 0; ee <= NEXP; ++ee) {
        int c = atomicAdd(&cnts[ee], 0);
        int nt = (c + 255) >> 8;
        for (int i = 0; i < nt; ++i) list[run + i] = ee * 16 + i;
        run += nt;
      }
      tot[0] = run * 4;
      qhead[0] = 0;
      for (int i = 0; i < MAXTILE; ++i) ready1[i] = 0;
      for (int i = 0; i < 40; ++i) cvt2[i] = 0;
    }
  }
}

// ---------------- k_moe: persistent work-queue — [GEMM1 tiles][w2 cvt][GEMM2 tiles] ----------------
// 256 blocks x 512 thr, 128 KiB LDS (1 block/CU). Queue item i: i<n -> GEMM1 tile i;
// n<=i<n+132 -> w2 fp32->bf16 quarter-convert; else GEMM2 tile i-n-132. Deps (all strictly
// earlier in queue): GEMM2 tile needs ready1[tile]==4 (its 4 GEMM1 xt-blocks, agent release)
// and cvt2[e]==4. Inner loop = r3-proven 8-phase counted-vmcnt schedule (T2+T3/T4+T5).

#define GLDS(gp, lp) __builtin_amdgcn_global_load_lds( \
    (const __attribute__((address_space(1))) void*)(gp), \
    (__attribute__((address_space(3))) void*)(lp), 16, 0, 0)

__global__ __launch_bounds__(512, 2) void k_moe(
    const u16* __restrict__ xb, const u16* __restrict__ w13b,
    u16* __restrict__ u_ws, u16* __restrict__ w2b, u16* __restrict__ oe_ws,
    const float* __restrict__ w2, const float* __restrict__ sw2,
    const int* __restrict__ etok, const int* __restrict__ cnts,
    const int* __restrict__ list, const int* __restrict__ tot,
    int* qhead, int* ready1, int* cvt2) {
  __shared__ u16 lds[65536];            // [dbuf 2][op 2][256*64], 128 KiB
  __shared__ int cur;
  const int tid = threadIdx.x;
  const int n = tot[0];
  const int nq = 2 * n + NCVT2;
  const int wave = tid >> 6, lane = tid & 63;
  const int wm = wave >> 2, wn = wave & 3;
  const int lr = lane & 15;
  const int lk = (lane >> 4) * 16;
  const char* ldsb = (const char*)lds;

  for (;;) {
    __syncthreads();                    // protect cur + lds reuse across items
    if (tid == 0) cur = __hip_atomic_fetch_add(qhead, 1, __ATOMIC_RELAXED, __HIP_MEMORY_SCOPE_AGENT);
    __syncthreads();
    const int it = cur;
    if (it >= nq) return;

    if (it >= n && it < n + NCVT2) {
      // ---- w2 quarter-convert: expert ec, rows [qt*256, qt*256+256) of H ----
      const int ci = it - n, ec = ci >> 2, qt = ci & 3;
      const float* src = ((ec < NEXP) ? w2 + ((size_t)ec << 19) : sw2) + (size_t)qt * 131072;
      u16* dst = w2b + ((size_t)ec << 19) + (size_t)qt * 131072;
      for (int ii = tid; ii < 16384; ii += 512) {
        float4 a4 = reinterpret_cast<const float4*>(src)[2*ii];
        float4 b4 = reinterpret_cast<const float4*>(src)[2*ii+1];
        ushort4 lo, hi;
        lo.x=f32_to_bf16(a4.x); lo.y=f32_to_bf16(a4.y); lo.z=f32_to_bf16(a4.z); lo.w=f32_to_bf16(a4.w);
        hi.x=f32_to_bf16(b4.x); hi.y=f32_to_bf16(b4.y); hi.z=f32_to_bf16(b4.z); hi.w=f32_to_bf16(b4.w);
        reinterpret_cast<ushort4*>(dst)[2*ii]   = lo;
        reinterpret_cast<ushort4*>(dst)[2*ii+1] = hi;
      }
      __syncthreads();                  // per-wave store drain before release
      if (tid == 0) __hip_atomic_fetch_add(&cvt2[ec], 1, __ATOMIC_RELEASE, __HIP_MEMORY_SCOPE_AGENT);
      continue;
    }

    // ---- GEMM tile ----
    const bool ph2 = (it >= n);
    const int wg = ph2 ? (it - n - NCVT2) : it;
    const int item = list[wg >> 2];
    const int e = item >> 4, yt = item & 15, xt = wg & 3;
    const int kdim = ph2 ? IDIM : HDIM;
    const int nt = kdim >> 6;
    const u16* Aq = ph2 ? u_ws : xb;
    const u16* Bq = (ph2 ? w2b : w13b) + (size_t)e * (size_t)(1024) * (size_t)kdim;
    u16* outq = ph2 ? oe_ws : u_ws;
    const int cnt = cnts[e];
    const int brow = yt * 256;
    const int rv = min(256, cnt - brow);
    const long rowbase = (long)e * CAPE;

    if (ph2) {                          // wait for my 4 producers + my B panel
      if (tid == 0) {
        while (__hip_atomic_load(&ready1[wg >> 2], __ATOMIC_RELAXED, __HIP_MEMORY_SCOPE_AGENT) < 4)
          __builtin_amdgcn_s_sleep(2);
        while (__hip_atomic_load(&cvt2[e], __ATOMIC_RELAXED, __HIP_MEMORY_SCOPE_AGENT) < 4)
          __builtin_amdgcn_s_sleep(2);
        (void)__hip_atomic_load(&ready1[wg >> 2], __ATOMIC_ACQUIRE, __HIP_MEMORY_SCOPE_AGENT); // inv L1/L2
      }
      __syncthreads();
    }

    const u16* pa[4]; const u16* pb[4];
#pragma unroll
    for (int j = 0; j < 4; ++j) {
      int row = j*64 + (tid >> 3);
      int sl = (tid & 7) ^ (row & 7);
      long arow;
      if (!ph2) arow = (row < rv) ? (long)etok[rowbase + brow + row] : 0L;
      else      arow = rowbase + brow + row;
      pa[j] = Aq + arow * kdim + sl * 8;
      pb[j] = Bq + ((long)(xt*256 + row)) * kdim + sl * 8;
    }

    auto STAGE = [&](int st, int op, int h) {
      if (st >= nt) st -= nt;                         // wrap (harmless re-stage of tile 0)
      int dbase = (st & 1) * 32768 + op * 16384;
      const u16* const* pp = op ? pb : pa;
#pragma unroll
      for (int s = 0; s < 2; ++s) {
        int j = h*2 + s;
        GLDS(pp[j] + st * 64, &lds[dbase + j*4096 + wave*512]);
      }
    };
    auto RD = [&](int d, int op, int rr, int kk) -> bf16x8 {
      int bc = (kk*64 + lk) ^ ((rr & 7) << 4);
      return *(const bf16x8*)(ldsb + (size_t)(d*65536 + op*32768 + rr*128 + bc));
    };

    f32x4 acc[8][4];
#pragma unroll
    for (int m = 0; m < 8; ++m)
#pragma unroll
      for (int nn = 0; nn < 4; ++nn) acc[m][nn] = (f32x4){0.f,0.f,0.f,0.f};

    // drain stale wrapped prefetches from the previous item (vmcnt counts would be wrong otherwise)
    asm volatile("s_waitcnt vmcnt(0)" ::: "memory");
    __builtin_amdgcn_sched_barrier(0);
    STAGE(0,0,0); STAGE(0,1,0); STAGE(0,0,1); STAGE(0,1,1);
    STAGE(1,0,0); STAGE(1,1,0); STAGE(1,1,1);
    asm volatile("s_waitcnt vmcnt(6)" ::: "memory");    // tile0's 8 loads landed
    __builtin_amdgcn_sched_barrier(0);
    __builtin_amdgcn_s_barrier();

    bf16x8 a[4][2], b[2][2], b0h[2][2];

    for (int t = 0; t < nt; ++t) {
      const int d = t & 1;
      // q0: read A0(8)+B0(4); stage A1(t+1)
#pragma unroll
      for (int m = 0; m < 4; ++m)
#pragma unroll
        for (int kk = 0; kk < 2; ++kk) a[m][kk] = RD(d, 0, wm*64 + m*16 + lr, kk);
#pragma unroll
      for (int nn = 0; nn < 2; ++nn)
#pragma unroll
        for (int kk = 0; kk < 2; ++kk) { b[nn][kk] = RD(d, 1, wn*32 + nn*16 + lr, kk); b0h[nn][kk] = b[nn][kk]; }
      STAGE(t+1, 0, 1);
      __builtin_amdgcn_s_barrier();
      asm volatile("s_waitcnt lgkmcnt(0)" ::: "memory");
      __builtin_amdgcn_sched_barrier(0);
      __builtin_amdgcn_s_setprio(1);
#pragma unroll
      for (int m = 0; m < 4; ++m)
#pragma unroll
        for (int nn = 0; nn < 2; ++nn)
#pragma unroll
          for (int kk = 0; kk < 2; ++kk)
            acc[m][nn] = __builtin_amdgcn_mfma_f32_16x16x32_bf16(a[m][kk], b[nn][kk], acc[m][nn], 0, 0, 0);
      __builtin_amdgcn_s_setprio(0);
      __builtin_amdgcn_sched_barrier(0);
      __builtin_amdgcn_s_barrier();
      // q1: read B1(4); stage B0(t+2)
#pragma unroll
      for (int nn = 0; nn < 2; ++nn)
#pragma unroll
        for (int kk = 0; kk < 2; ++kk) b[nn][kk] = RD(d, 1, 128 + wn*32 + nn*16 + lr, kk);
      STAGE(t+2, 1, 0);
      __builtin_amdgcn_s_barrier();
      asm volatile("s_waitcnt lgkmcnt(0)" ::: "memory");
      __builtin_amdgcn_sched_barrier(0);
      __builtin_amdgcn_s_setprio(1);
#pragma unroll
      for (int m = 0; m < 4; ++m)
#pragma unroll
        for (int nn = 0; nn < 2; ++nn)
#pragma unroll
          for (int kk = 0; kk < 2; ++kk)
            acc[m][2+nn] = __builtin_amdgcn_mfma_f32_16x16x32_bf16(a[m][kk], b[nn][kk], acc[m][2+nn], 0, 0, 0);
      __builtin_amdgcn_s_setprio(0);
      __builtin_amdgcn_sched_barrier(0);
      __builtin_amdgcn_s_barrier();
      // q2: read A1(8); stage A0(t+2)
#pragma unroll
      for (int m = 0; m < 4; ++m)
#pragma unroll
        for (int kk = 0; kk < 2; ++kk) a[m][kk] = RD(d, 0, 128 + wm*64 + m*16 + lr, kk);
      STAGE(t+2, 0, 0);
      __builtin_amdgcn_s_barrier();
      asm volatile("s_waitcnt lgkmcnt(0)" ::: "memory");
      __builtin_amdgcn_sched_barrier(0);
      __builtin_amdgcn_s_setprio(1);
#pragma unroll
      for (int m = 0; m < 4; ++m)
#pragma unroll
        for (int nn = 0; nn < 2; ++nn)
#pragma unroll
          for (int kk = 0; kk < 2; ++kk)
            acc[4+m][2+nn] = __builtin_amdgcn_mfma_f32_16x16x32_bf16(a[m][kk], b[nn][kk], acc[4+m][2+nn], 0, 0, 0);
      __builtin_amdgcn_s_setprio(0);
      __builtin_amdgcn_sched_barrier(0);
      __builtin_amdgcn_s_barrier();
      // q3: no ds_reads (A1 + held B0); stage B1(t+2)
      STAGE(t+2, 1, 1);
      __builtin_amdgcn_s_barrier();
      asm volatile("s_waitcnt lgkmcnt(0)" ::: "memory");
      __builtin_amdgcn_sched_barrier(0);
      __builtin_amdgcn_s_setprio(1);
#pragma unroll
      for (int m = 0; m < 4; ++m)
#pragma unroll
        for (int nn = 0; nn < 2; ++nn)
#pragma unroll
          for (int kk = 0; kk < 2; ++kk)
            acc[4+m][nn] = __builtin_amdgcn_mfma_f32_16x16x32_bf16(a[m][kk], b0h[nn][kk], acc[4+m][nn], 0, 0, 0);
      __builtin_amdgcn_s_setprio(0);
      __builtin_amdgcn_sched_barrier(0);
      asm volatile("s_waitcnt vmcnt(6)" ::: "memory");  // K-tile boundary: tile t+1 fully landed
      __builtin_amdgcn_s_barrier();
    }

    // epilogue: C/D map col=lane&15, row=(lane>>4)*4+reg  [verified m89]
    const int rl = (lane >> 4) << 2;
    if (!ph2) {
#pragma unroll
      for (int mq = 0; mq < 2; ++mq)
#pragma unroll
        for (int m = 0; m < 4; ++m) {
          int rbase = mq*128 + wm*64 + m*16 + rl;
#pragma unroll
          for (int nqq = 0; nqq < 2; ++nqq) {
            f32x4 h1 = acc[mq*4+m][nqq*2], h3 = acc[mq*4+m][nqq*2+1];
            int ucol = xt*128 + nqq*64 + wn*16 + lr;
#pragma unroll
            for (int j = 0; j < 4; ++j) {
              int lrow = rbase + j;
              if (lrow < rv) {
                float v1 = h1[j];
                float uu = v1 / (1.f + __expf(-v1)) * h3[j];   // silu(h1)*h3
                outq[(size_t)(rowbase + brow + lrow) * IDIM + ucol] = f32_to_bf16(uu);
              }
            }
          }
        }
      __syncthreads();                  // all waves' stores drained (waitcnt before barrier)
      if (tid == 0) __hip_atomic_fetch_add(&ready1[wg >> 2], 1, __ATOMIC_RELEASE, __HIP_MEMORY_SCOPE_AGENT);
    } else {
#pragma unroll
      for (int mq = 0; mq < 2; ++mq)
#pragma unroll
        for (int m = 0; m < 4; ++m) {
          int rbase = mq*128 + wm*64 + m*16 + rl;
#pragma unroll
          for (int nqq = 0; nqq < 2; ++nqq)
#pragma unroll
            for (int nn = 0; nn < 2; ++nn) {
              int col = xt*256 + nqq*128 + wn*32 + nn*16 + lr;
              f32x4 v = acc[mq*4+m][nqq*2+nn];
#pragma unroll
              for (int j = 0; j < 4; ++j) {
                int lrow = rbase + j;
                if (lrow < rv)
                  outq[(size_t)(rowbase + brow + lrow) * HDIM + col] = f32_to_bf16(v[j]);
              }
            }
        }
    }
  }
}

// ---------------- combine: y[t] = sum_k w_k * oe[e_k][pos_k] + shared[t] ----------------
__global__ __launch_bounds__(256) void k_combine(const u16* __restrict__ oe,
                                                 const int* __restrict__ idx, const float* __restrict__ wts,
                                                 const int* __restrict__ pos, float* __restrict__ y) {
  int t = blockIdx.x;
  int h0 = threadIdx.x * 4;
  float a0 = 0, a1 = 0, a2 = 0, a3 = 0;
#pragma unroll
  for (int k = 0; k < KSEL; ++k) {
    int e = idx[t*KSEL + k];
    int p = pos[t*KSEL + k];
    if (p < CAPE) {
      float w = wts[t*KSEL + k];
      ushort4 v = *reinterpret_cast<const ushort4*>(oe + ((long)e * CAPE + p) * HDIM + h0);
      a0 += w * bf16_to_f32(v.x); a1 += w * bf16_to_f32(v.y);
      a2 += w * bf16_to_f32(v.z); a3 += w * bf16_to_f32(v.w);
    }
  }
  ushort4 s = *reinterpret_cast<const ushort4*>(oe + ((long)NEXP * CAPE + t) * HDIM + h0);
  a0 += bf16_to_f32(s.x); a1 += bf16_to_f32(s.y); a2 += bf16_to_f32(s.z); a3 += bf16_to_f32(s.w);
  float4 o2; o2.x = a0; o2.y = a1; o2.z = a2; o2.w = a3;
  reinterpret_cast<float4*>(y + (long)t * HDIM)[threadIdx.x] = o2;
}

extern "C" void kernel_launch(void* const* d_in, const int* in_sizes, int n_in,
                              void* d_out, int out_size, void* d_ws, size_t ws_size,
                              hipStream_t stream) {
  const float* x      = (const float*)d_in[0];
  const float* gate_w = (const float*)d_in[1];
  const float* w13    = (const float*)d_in[2];
  const float* w2     = (const float*)d_in[3];
  const float* sw1    = (const float*)d_in[4];
  const float* sw2    = (const float*)d_in[5];
  const float* sw3    = (const float*)d_in[6];
  float* y = (float*)d_out;

  char* base = (char*)d_ws;
  size_t off = 0;
  auto alloc = [&](size_t bytes) -> void* {
    void* p = base + off;
    off = (off + bytes + 255) & ~(size_t)255;
    return p;
  };
  u16* xb    = (u16*)alloc((size_t)T_TOK * HDIM * 2);
  u16* w13b  = (u16*)alloc((size_t)(NEXP + 1) * 2 * IDIM * HDIM * 2);
  u16* w2b   = (u16*)alloc((size_t)(NEXP + 1) * HDIM * IDIM * 2);
  u16* u_ws  = (u16*)alloc((size_t)NROW * IDIM * 2);
  u16* oe_ws = (u16*)alloc((size_t)NROW * HDIM * 2);
  int*   idx  = (int*)alloc((size_t)T_TOK * KSEL * 4);
  float* wts  = (float*)alloc((size_t)T_TOK * KSEL * 4);
  int*   pos  = (int*)alloc((size_t)T_TOK * KSEL * 4);
  int*   etok = (int*)alloc((size_t)NROW * 4);
  int*   cnts = (int*)alloc(256);
  int*   list = (int*)alloc(MAXTILE * 4);
  int*   tot  = (int*)alloc(64);
  int*   done = (int*)alloc(64);
  int*   qhead  = (int*)alloc(64);
  int*   ready1 = (int*)alloc(MAXTILE * 4);
  int*   cvt2   = (int*)alloc(40 * 4);
  if (off > ws_size) return;

  // 1. gate (128 blocks) || w13+sw1/sw3 -> bf16 interleave convert (2048 blocks)
  k_pre<<<dim3(2176), dim3(256), 0, stream>>>(x, gate_w, w13, sw1, sw3, idx, wts, xb, w13b, done);
  // 2. capacity assignment + work-list scheduler + queue-state reset
  k_assign<<<dim3(NEXP + 1), dim3(1024), 0, stream>>>(idx, etok, pos, cnts, list, tot, done,
                                                      qhead, ready1, cvt2);
  // 3. persistent merged GEMM1 -> w2cvt -> GEMM2 queue (1 block/CU)
  k_moe<<<dim3(256), dim3(512), 0, stream>>>(xb, w13b, u_ws, w2b, oe_ws, w2, sw2,
                                             etok, cnts, list, tot, qhead, ready1, cvt2);
  // 4. combine
  k_combine<<<dim3(T_TOK), dim3(256), 0, stream>>>(oe_ws, idx, wts, pos, y);
}

// Round 7
// 285.558 us; speedup vs baseline: 1.1914x; 1.1914x over previous
//
#include <hip/hip_runtime.h>

typedef unsigned short u16;
typedef unsigned int u32;
typedef float f32x4 __attribute__((ext_vector_type(4)));
typedef __bf16 bf16x8 __attribute__((ext_vector_type(8)));

#define T_TOK 4096
#define HDIM 1024
#define IDIM 512
#define NEXP 32
#define KSEL 8
#define CAPE 2048
#define NROW (NEXP*CAPE + T_TOK)   // 69632 rows total (experts + shared)
#define MAXTILE 528                // 33 experts * 16 y-tiles max
#define MAXWG  (MAXTILE*4)         // 2112
#define CVTWG  512                 // guaranteed converter blocks appended to GEMM1

__device__ __forceinline__ u16 f32_to_bf16(float f) {
  u32 x = __float_as_uint(f);
  u32 r = (x + 0x7FFFu + ((x >> 16) & 1u)) >> 16;   // RNE; inputs finite
  return (u16)r;
}
__device__ __forceinline__ float bf16_to_f32(u16 u) {
  return __uint_as_float(((u32)u) << 16);
}

// ---------------- k_pre: gate (0..127) ∪ assign (128..160, gated) ∪ w13 convert (161..2208) --------
// Gate: fp64 logits, group-limited top-k on logits (sigmoid monotonic), sigmoid only for winners;
// fused x->bf16; RELEASE-increment done[0]. Assign blocks (dispatched early, hold CUs) spin on
// done[0]==128 (+one ACQUIRE for cross-XCD stale-L2 safety), then ballot-scan capacity; last
// finisher (done[1]) builds the compact tile list. Convert: w13(+sw1/sw3) -> bf16 w1/w3 interleave.
__global__ __launch_bounds__(256) void k_pre(const float* __restrict__ x, const float* __restrict__ gw,
                                             const float* __restrict__ w13,
                                             const float* __restrict__ sw1, const float* __restrict__ sw3,
                                             int* __restrict__ idx, float* __restrict__ wts,
                                             u16* __restrict__ xb, u16* __restrict__ w13b,
                                             int* __restrict__ etok, int* __restrict__ pos,
                                             int* __restrict__ cnts,
                                             int* __restrict__ list, int* __restrict__ tot,
                                             int* __restrict__ done) {
  const int tid = threadIdx.x;
  if (blockIdx.x >= 161) {
    // ---- w13 convert: chunk j of 8 f32; dest row rd: c=rd>>4, even c -> w1 rows (c>>1)*16.., odd -> w3
    const long n8 = (long)(NEXP + 1) * 1024 * 128;
    const long stride = (long)(2209 - 161) * 256;
    for (long j = (long)(blockIdx.x - 161) * 256 + tid; j < n8; j += stride) {
      int e   = (int)(j >> 17);
      int rem = (int)(j & 131071);
      int rowd = rem >> 7;
      int c8   = rem & 127;
      int c = rowd >> 4, cw = rowd & 15;
      int srow = (c >> 1) * 16 + cw;
      int sel = c & 1;
      const float* s;
      if (e < NEXP) s = w13 + (size_t)e * (2 * IDIM * HDIM) + (size_t)(sel * IDIM + srow) * HDIM + c8 * 8;
      else          s = (sel ? sw3 : sw1) + (size_t)srow * HDIM + c8 * 8;
      float4 a = reinterpret_cast<const float4*>(s)[0];
      float4 b = reinterpret_cast<const float4*>(s)[1];
      ushort4 lo, hi;
      lo.x=f32_to_bf16(a.x); lo.y=f32_to_bf16(a.y); lo.z=f32_to_bf16(a.z); lo.w=f32_to_bf16(a.w);
      hi.x=f32_to_bf16(b.x); hi.y=f32_to_bf16(b.y); hi.z=f32_to_bf16(b.z); hi.w=f32_to_bf16(b.w);
      u16* d = w13b + ((size_t)e * 1024 + rowd) * HDIM + c8 * 8;
      reinterpret_cast<ushort4*>(d)[0] = lo;
      reinterpret_cast<ushort4*>(d)[1] = hi;
    }
    return;
  }
  if (blockIdx.x >= 128) {
    // ---- assign path (gated on all 128 gate blocks) ----
    const int e = blockIdx.x - 128;
    if (tid == 0) {
      while (__hip_atomic_load(&done[0], __ATOMIC_RELAXED, __HIP_MEMORY_SCOPE_AGENT) < 128)
        __builtin_amdgcn_s_sleep(2);
      (void)__hip_atomic_load(&done[0], __ATOMIC_ACQUIRE, __HIP_MEMORY_SCOPE_AGENT);  // inv stale L1/L2
    }
    __syncthreads();
    int base = 0;
    if (e == NEXP) {                             // shared "expert": identity token list
      for (int t = tid; t < T_TOK; t += 256) etok[NEXP*CAPE + t] = t;
      base = T_TOK;
    } else {
      __shared__ int wbase[5];
      const int wid = tid >> 6, lane = tid & 63;
      for (int c = 0; c < T_TOK / 256; ++c) {
        int t = c * 256 + tid;
        int found = -1;
#pragma unroll
        for (int k = 0; k < KSEL; ++k) if (idx[t*KSEL + k] == e) found = k;
        unsigned long long mask = __ballot(found >= 0);
        int myrank = __popcll(mask & ((1ull << lane) - 1ull));
        __syncthreads();
        if (lane == 0) wbase[wid] = __popcll(mask);
        __syncthreads();
        if (tid == 0) {
          int run = 0;
#pragma unroll
          for (int w = 0; w < 4; ++w) { int v = wbase[w]; wbase[w] = run; run += v; }
          wbase[4] = run;
        }
        __syncthreads();
        if (found >= 0) {
          int slot = base + wbase[wid] + myrank;
          pos[t*KSEL + found] = slot;
          if (slot < CAPE) etok[e*CAPE + slot] = t;
        }
        base += wbase[4];
        __syncthreads();
      }
      base = min(base, CAPE);
    }
    if (tid == 0) {
      cnts[e] = base;
      __threadfence();
      if (__hip_atomic_fetch_add(&done[1], 1, __ATOMIC_RELEASE, __HIP_MEMORY_SCOPE_AGENT) == NEXP) {
        __threadfence();
        int run = 0;
        for (int ee = 0; ee <= NEXP; ++ee) {
          int c = atomicAdd(&cnts[ee], 0);       // device-scope read
          int nt = (c + 255) >> 8;
          for (int i = 0; i < nt; ++i) list[run + i] = ee * 16 + i;
          run += nt;
        }
        tot[0] = run * 4;
      }
    }
    return;
  }
  // ---- gate path ----
  __shared__ float xs[32][129];
  __shared__ float gs_[32][129];
  __shared__ double sc[32][32];
  const int t0 = blockIdx.x * 32;
  const int tl = tid & 31, g = tid >> 5;
  double acc0 = 0, acc1 = 0, acc2 = 0, acc3 = 0;
  for (int k0 = 0; k0 < HDIM; k0 += 128) {
#pragma unroll
    for (int q = 0; q < 4; ++q) {
      int f = tid + 256 * q;
      int row = f >> 5, c4 = (f & 31) * 4;
      float4 v = *reinterpret_cast<const float4*>(x + (long)(t0 + row) * HDIM + k0 + c4);
      xs[row][c4+0]=v.x; xs[row][c4+1]=v.y; xs[row][c4+2]=v.z; xs[row][c4+3]=v.w;
      ushort4 xv; xv.x=f32_to_bf16(v.x); xv.y=f32_to_bf16(v.y); xv.z=f32_to_bf16(v.z); xv.w=f32_to_bf16(v.w);
      *reinterpret_cast<ushort4*>(xb + (long)(t0 + row) * HDIM + k0 + c4) = xv;
      float4 w = *reinterpret_cast<const float4*>(gw + (long)row * HDIM + k0 + c4);
      gs_[row][c4+0]=w.x; gs_[row][c4+1]=w.y; gs_[row][c4+2]=w.z; gs_[row][c4+3]=w.w;
    }
    __syncthreads();
#pragma unroll 4
    for (int kk = 0; kk < 128; ++kk) {
      double xv = (double)xs[tl][kk];
      acc0 += xv * (double)gs_[g     ][kk];
      acc1 += xv * (double)gs_[g +  8][kk];
      acc2 += xv * (double)gs_[g + 16][kk];
      acc3 += xv * (double)gs_[g + 24][kk];
    }
    __syncthreads();
  }
  sc[tl][g     ] = acc0;
  sc[tl][g +  8] = acc1;
  sc[tl][g + 16] = acc2;
  sc[tl][g + 24] = acc3;
  __syncthreads();
  if (tid < 32) {
    int t = t0 + tid;
    double gsc[8];
#pragma unroll
    for (int gg = 0; gg < 8; ++gg) {
      double mx = sc[tid][4*gg];
#pragma unroll
      for (int j = 1; j < 4; ++j) mx = fmax(mx, sc[tid][4*gg + j]);
      gsc[gg] = mx;
    }
    unsigned gmask = 0;
    for (int it = 0; it < 4; ++it) {          // top-4 groups, strict >, first index wins
      double best = -1e300; int bi = 0;
      for (int gg = 0; gg < 8; ++gg)
        if (!((gmask >> gg) & 1) && gsc[gg] > best) { best = gsc[gg]; bi = gg; }
      gmask |= 1u << bi;
    }
    unsigned emask = 0; int ei[KSEL]; double ew[KSEL]; double wsum = 0;
    for (int it = 0; it < KSEL; ++it) {       // top-8 experts on logits
      double best = -1e300; int bi = 0;
      for (int e = 0; e < NEXP; ++e)
        if (((gmask >> (e >> 2)) & 1) && !((emask >> e) & 1)) {
          double v = sc[tid][e];
          if (v > best) { best = v; bi = e; }
        }
      emask |= 1u << bi; ei[it] = bi;
      double sg = 1.0 / (1.0 + exp(-best));   // sigmoid only for selected
      ew[it] = sg; wsum += sg;
    }
    double s = 2.5 / (wsum + 1e-20);
    for (int k = 0; k < KSEL; ++k) { idx[t*KSEL + k] = ei[k]; wts[t*KSEL + k] = (float)(ew[k] * s); }
  }
  __syncthreads();
  if (tid == 0) {
    __threadfence();
    __hip_atomic_fetch_add(&done[0], 1, __ATOMIC_RELEASE, __HIP_MEMORY_SCOPE_AGENT);
  }
}

// ---------------- grouped GEMM: 256x256 tile, BK=64, 8-phase counted-vmcnt schedule ----------------
// r3-proven inner loop: T1 bijective XCD swizzle over active prefix + T2 XOR LDS swizzle +
// T3/T4 8-phase counted vmcnt(6) + T5 setprio. Blocks beyond the active prefix run the
// fp32->bf16 converter for the NEXT GEMM's B (w2/sw2) instead of exiting (cvt_n8>0 only on GEMM1).

#define GLDS(gp, lp) __builtin_amdgcn_global_load_lds( \
    (const __attribute__((address_space(1))) void*)(gp), \
    (__attribute__((address_space(3))) void*)(lp), 16, 0, 0)

template<int KDIM, bool GATHER, bool ACT>
__global__ __launch_bounds__(512, 2) void k_gemm8(const u16* __restrict__ A, const u16* __restrict__ Ball,
                                                  u16* __restrict__ out,
                                                  const int* __restrict__ etok, const int* __restrict__ cnts,
                                                  const int* __restrict__ list, const int* __restrict__ tot,
                                                  const float* __restrict__ cvsrc, const float* __restrict__ cvsrc2,
                                                  u16* __restrict__ cvdst, long cvt_n8) {
  constexpr int NT = KDIM / 64;
  constexpr int MSK = NT - 1;
  __shared__ u16 lds[65536];            // [dbuf 2][op 2][256*64], 128 KiB

  const int n = tot[0];                 // active wg count (4 * tiles)
  const int bid0 = blockIdx.x;
  const int tid = threadIdx.x;
  if (bid0 >= n) {
    // ---- converter service: stream cvsrc (E experts) + cvsrc2 (shared) -> cvdst bf16 ----
    if (cvt_n8 > 0) {
      const long nb = (long)gridDim.x - n;
      const long stride = nb * 512;
      for (long j = (long)(bid0 - n) * 512 + tid; j < cvt_n8; j += stride) {
        int e   = (int)(j >> 16);                    // 65536 chunks per expert (H*I/8)
        int rem = (int)(j & 65535);
        const float* s = ((e < NEXP) ? cvsrc + ((size_t)e << 19) : cvsrc2) + (size_t)rem * 8;
        float4 a = reinterpret_cast<const float4*>(s)[0];
        float4 b = reinterpret_cast<const float4*>(s)[1];
        ushort4 lo, hi;
        lo.x=f32_to_bf16(a.x); lo.y=f32_to_bf16(a.y); lo.z=f32_to_bf16(a.z); lo.w=f32_to_bf16(a.w);
        hi.x=f32_to_bf16(b.x); hi.y=f32_to_bf16(b.y); hi.z=f32_to_bf16(b.z); hi.w=f32_to_bf16(b.w);
        u16* d = cvdst + ((size_t)e << 19) + (size_t)rem * 8;
        reinterpret_cast<ushort4*>(d)[0] = lo;
        reinterpret_cast<ushort4*>(d)[1] = hi;
      }
    }
    return;
  }
  // m204 bijective XCD swizzle over [0,n)
  const int q = n >> 3, r = n & 7, xc = bid0 & 7, o = bid0 >> 3;
  const int wg = (xc < r ? xc * (q + 1) : r * (q + 1) + (xc - r) * q) + o;
  const int item = list[wg >> 2];
  const int e = item >> 4, yt = item & 15, xt = wg & 3;

  const int cnt = cnts[e];
  const int brow = yt * 256;
  const int rv = min(256, cnt - brow);
  const long rowbase = (long)e * CAPE;
  const u16* Bexp = Ball + (size_t)e * (size_t)(1024 * KDIM);

  const int wave = tid >> 6, lane = tid & 63;
  const int wm = wave >> 2, wn = wave & 3;
  const int lr = lane & 15;
  const int lk = (lane >> 4) * 16;      // byte offset of this lane's K-slot

  // staging source pointers: sub-issue j covers tile rows j*64..j*64+63
  const u16* pa[4]; const u16* pb[4];
#pragma unroll
  for (int j = 0; j < 4; ++j) {
    int row = j*64 + (tid >> 3);
    int sl = (tid & 7) ^ (row & 7);                  // pre-swizzled source chunk
    long arow;
    if (GATHER) arow = (row < rv) ? (long)etok[rowbase + brow + row] : 0L;
    else        arow = rowbase + brow + row;
    pa[j] = A + arow * KDIM + sl * 8;
    pb[j] = Bexp + ((long)(xt*256 + row)) * KDIM + sl * 8;
  }

  // stage half h (0: rows 0-127, 1: rows 128-255) of operand op of K-tile st
  auto STAGE = [&](int st, int op, int h) {
    int dbase = (st & 1) * 32768 + op * 16384;
    const u16* const* pp = op ? pb : pa;
#pragma unroll
    for (int s = 0; s < 2; ++s) {
      int j = h*2 + s;
      GLDS(pp[j] + st * 64, &lds[dbase + j*4096 + wave*512]);
    }
  };

  const char* ldsb = (const char*)lds;
  auto RD = [&](int d, int op, int rr, int kk) -> bf16x8 {
    int bc = (kk*64 + lk) ^ ((rr & 7) << 4);
    return *(const bf16x8*)(ldsb + (size_t)(d*65536 + op*32768 + rr*128 + bc));
  };

  f32x4 acc[8][4];
#pragma unroll
  for (int m = 0; m < 8; ++m)
#pragma unroll
    for (int nn = 0; nn < 4; ++nn) acc[m][nn] = (f32x4){0.f,0.f,0.f,0.f};

  // prologue: tile0 fully, tile1 {A0,B0,B1}; A1(1) staged at t=0.q0
  STAGE(0,0,0); STAGE(0,1,0); STAGE(0,0,1); STAGE(0,1,1);
  STAGE(1,0,0); STAGE(1,1,0); STAGE(1,1,1);
  asm volatile("s_waitcnt vmcnt(6)" ::: "memory");    // tile0's 8 loads landed
  __builtin_amdgcn_sched_barrier(0);
  __builtin_amdgcn_s_barrier();

  bf16x8 a[4][2], b[2][2], b0h[2][2];

  for (int t = 0; t < NT; ++t) {
    const int d = t & 1;
    // ---------- q0: (mq=0,nq=0) — read A0(8)+B0(4); stage A1(t+1) ----------
#pragma unroll
    for (int m = 0; m < 4; ++m)
#pragma unroll
      for (int kk = 0; kk < 2; ++kk) a[m][kk] = RD(d, 0, wm*64 + m*16 + lr, kk);
#pragma unroll
    for (int nn = 0; nn < 2; ++nn)
#pragma unroll
      for (int kk = 0; kk < 2; ++kk) { b[nn][kk] = RD(d, 1, wn*32 + nn*16 + lr, kk); b0h[nn][kk] = b[nn][kk]; }
    STAGE((t+1) & MSK, 0, 1);
    __builtin_amdgcn_s_barrier();
    asm volatile("s_waitcnt lgkmcnt(0)" ::: "memory");
    __builtin_amdgcn_sched_barrier(0);
    __builtin_amdgcn_s_setprio(1);
#pragma unroll
    for (int m = 0; m < 4; ++m)
#pragma unroll
      for (int nn = 0; nn < 2; ++nn)
#pragma unroll
        for (int kk = 0; kk < 2; ++kk)
          acc[m][nn] = __builtin_amdgcn_mfma_f32_16x16x32_bf16(a[m][kk], b[nn][kk], acc[m][nn], 0, 0, 0);
    __builtin_amdgcn_s_setprio(0);
    __builtin_amdgcn_sched_barrier(0);
    __builtin_amdgcn_s_barrier();
    // ---------- q1: (mq=0,nq=1) — read B1(4); stage B0(t+2) ----------
#pragma unroll
    for (int nn = 0; nn < 2; ++nn)
#pragma unroll
      for (int kk = 0; kk < 2; ++kk) b[nn][kk] = RD(d, 1, 128 + wn*32 + nn*16 + lr, kk);
    STAGE((t+2) & MSK, 1, 0);
    __builtin_amdgcn_s_barrier();
    asm volatile("s_waitcnt lgkmcnt(0)" ::: "memory");
    __builtin_amdgcn_sched_barrier(0);
    __builtin_amdgcn_s_setprio(1);
#pragma unroll
    for (int m = 0; m < 4; ++m)
#pragma unroll
      for (int nn = 0; nn < 2; ++nn)
#pragma unroll
        for (int kk = 0; kk < 2; ++kk)
          acc[m][2+nn] = __builtin_amdgcn_mfma_f32_16x16x32_bf16(a[m][kk], b[nn][kk], acc[m][2+nn], 0, 0, 0);
    __builtin_amdgcn_s_setprio(0);
    __builtin_amdgcn_sched_barrier(0);
    __builtin_amdgcn_s_barrier();
    // ---------- q2: (mq=1,nq=1) — read A1(8); stage A0(t+2) ----------
#pragma unroll
    for (int m = 0; m < 4; ++m)
#pragma unroll
      for (int kk = 0; kk < 2; ++kk) a[m][kk] = RD(d, 0, 128 + wm*64 + m*16 + lr, kk);
    STAGE((t+2) & MSK, 0, 0);
    __builtin_amdgcn_s_barrier();
    asm volatile("s_waitcnt lgkmcnt(0)" ::: "memory");
    __builtin_amdgcn_sched_barrier(0);
    __builtin_amdgcn_s_setprio(1);
#pragma unroll
    for (int m = 0; m < 4; ++m)
#pragma unroll
      for (int nn = 0; nn < 2; ++nn)
#pragma unroll
        for (int kk = 0; kk < 2; ++kk)
          acc[4+m][2+nn] = __builtin_amdgcn_mfma_f32_16x16x32_bf16(a[m][kk], b[nn][kk], acc[4+m][2+nn], 0, 0, 0);
    __builtin_amdgcn_s_setprio(0);
    __builtin_amdgcn_sched_barrier(0);
    __builtin_amdgcn_s_barrier();
    // ---------- q3: (mq=1,nq=0) — no ds_reads (A1 + held B0); stage B1(t+2) ----------
    STAGE((t+2) & MSK, 1, 1);
    __builtin_amdgcn_s_barrier();
    asm volatile("s_waitcnt lgkmcnt(0)" ::: "memory");
    __builtin_amdgcn_sched_barrier(0);
    __builtin_amdgcn_s_setprio(1);
#pragma unroll
    for (int m = 0; m < 4; ++m)
#pragma unroll
      for (int nn = 0; nn < 2; ++nn)
#pragma unroll
        for (int kk = 0; kk < 2; ++kk)
          acc[4+m][nn] = __builtin_amdgcn_mfma_f32_16x16x32_bf16(a[m][kk], b0h[nn][kk], acc[4+m][nn], 0, 0, 0);
    __builtin_amdgcn_s_setprio(0);
    __builtin_amdgcn_sched_barrier(0);
    asm volatile("s_waitcnt vmcnt(6)" ::: "memory");    // K-tile boundary: tile t+1 fully landed
    __builtin_amdgcn_s_barrier();
  }

  // epilogue: C/D map col=lane&15, row=(lane>>4)*4+reg  [verified m89]
  const int rl = (lane >> 4) << 2;
  if (ACT) {
#pragma unroll
    for (int mq = 0; mq < 2; ++mq)
#pragma unroll
      for (int m = 0; m < 4; ++m) {
        int rbase = mq*128 + wm*64 + m*16 + rl;
#pragma unroll
        for (int nq = 0; nq < 2; ++nq) {
          f32x4 h1 = acc[mq*4+m][nq*2], h3 = acc[mq*4+m][nq*2+1];
          int ucol = xt*128 + nq*64 + wn*16 + lr;
#pragma unroll
          for (int j = 0; j < 4; ++j) {
            int lrow = rbase + j;
            if (lrow < rv) {
              float v1 = h1[j];
              float uu = v1 / (1.f + __expf(-v1)) * h3[j];   // silu(h1)*h3
              out[(size_t)(rowbase + brow + lrow) * IDIM + ucol] = f32_to_bf16(uu);
            }
          }
        }
      }
  } else {
#pragma unroll
    for (int mq = 0; mq < 2; ++mq)
#pragma unroll
      for (int m = 0; m < 4; ++m) {
        int rbase = mq*128 + wm*64 + m*16 + rl;
#pragma unroll
        for (int nq = 0; nq < 2; ++nq)
#pragma unroll
          for (int nn = 0; nn < 2; ++nn) {
            int col = xt*256 + nq*128 + wn*32 + nn*16 + lr;
            f32x4 v = acc[mq*4+m][nq*2+nn];
#pragma unroll
            for (int j = 0; j < 4; ++j) {
              int lrow = rbase + j;
              if (lrow < rv)
                out[(size_t)(rowbase + brow + lrow) * HDIM + col] = f32_to_bf16(v[j]);
            }
          }
      }
  }
}

// ---------------- combine: y[t] = sum_k w_k * oe[e_k][pos_k] + shared[t] ----------------
__global__ __launch_bounds__(256) void k_combine(const u16* __restrict__ oe,
                                                 const int* __restrict__ idx, const float* __restrict__ wts,
                                                 const int* __restrict__ pos, float* __restrict__ y) {
  int t = blockIdx.x;
  int h0 = threadIdx.x * 4;
  float a0 = 0, a1 = 0, a2 = 0, a3 = 0;
#pragma unroll
  for (int k = 0; k < KSEL; ++k) {
    int e = idx[t*KSEL + k];
    int p = pos[t*KSEL + k];
    if (p < CAPE) {
      float w = wts[t*KSEL + k];
      ushort4 v = *reinterpret_cast<const ushort4*>(oe + ((long)e * CAPE + p) * HDIM + h0);
      a0 += w * bf16_to_f32(v.x); a1 += w * bf16_to_f32(v.y);
      a2 += w * bf16_to_f32(v.z); a3 += w * bf16_to_f32(v.w);
    }
  }
  ushort4 s = *reinterpret_cast<const ushort4*>(oe + ((long)NEXP * CAPE + t) * HDIM + h0);
  a0 += bf16_to_f32(s.x); a1 += bf16_to_f32(s.y); a2 += bf16_to_f32(s.z); a3 += bf16_to_f32(s.w);
  float4 o2; o2.x = a0; o2.y = a1; o2.z = a2; o2.w = a3;
  reinterpret_cast<float4*>(y + (long)t * HDIM)[threadIdx.x] = o2;
}

extern "C" void kernel_launch(void* const* d_in, const int* in_sizes, int n_in,
                              void* d_out, int out_size, void* d_ws, size_t ws_size,
                              hipStream_t stream) {
  const float* x      = (const float*)d_in[0];
  const float* gate_w = (const float*)d_in[1];
  const float* w13    = (const float*)d_in[2];
  const float* w2     = (const float*)d_in[3];
  const float* sw1    = (const float*)d_in[4];
  const float* sw2    = (const float*)d_in[5];
  const float* sw3    = (const float*)d_in[6];
  float* y = (float*)d_out;

  char* base = (char*)d_ws;
  size_t off = 0;
  auto alloc = [&](size_t bytes) -> void* {
    void* p = base + off;
    off = (off + bytes + 255) & ~(size_t)255;
    return p;
  };
  u16* xb    = (u16*)alloc((size_t)T_TOK * HDIM * 2);
  u16* w13b  = (u16*)alloc((size_t)(NEXP + 1) * 2 * IDIM * HDIM * 2);
  u16* w2b   = (u16*)alloc((size_t)(NEXP + 1) * HDIM * IDIM * 2);
  u16* u_ws  = (u16*)alloc((size_t)NROW * IDIM * 2);
  u16* oe_ws = (u16*)alloc((size_t)NROW * HDIM * 2);
  int*   idx  = (int*)alloc((size_t)T_TOK * KSEL * 4);
  float* wts  = (float*)alloc((size_t)T_TOK * KSEL * 4);
  int*   pos  = (int*)alloc((size_t)T_TOK * KSEL * 4);
  int*   etok = (int*)alloc((size_t)NROW * 4);
  int*   cnts = (int*)alloc(256);
  int*   list = (int*)alloc(MAXTILE * 4);
  int*   tot  = (int*)alloc(64);
  int*   done = (int*)alloc(64);
  if (off > ws_size) return;

  // reset gate/assign rendezvous counters (graph-capture-safe)
  hipMemsetAsync(done, 0, 64, stream);

  // 1. gate (128) ∪ assign (33, gated on gates) ∪ w13+sw1/sw3 bf16 interleave convert (2048)
  k_pre<<<dim3(2209), dim3(256), 0, stream>>>(x, gate_w, w13, sw1, sw3, idx, wts, xb, w13b,
                                              etok, pos, cnts, list, tot, done);
  // 2. GEMM1 (bf16 w13b); inactive blocks convert w2+sw2 -> w2b in GEMM1's shadow
  k_gemm8<HDIM, true,  true ><<<dim3(MAXWG + CVTWG), dim3(512), 0, stream>>>(
      xb, w13b, u_ws, etok, cnts, list, tot,
      w2, sw2, w2b, (long)(NEXP + 1) * HDIM * IDIM / 8);
  // 3. GEMM2 (bf16 w2b)
  k_gemm8<IDIM, false, false><<<dim3(MAXWG), dim3(512), 0, stream>>>(
      u_ws, w2b, oe_ws, etok, cnts, list, tot,
      nullptr, nullptr, nullptr, 0L);
  // 4. combine
  k_combine<<<dim3(T_TOK), dim3(256), 0, stream>>>(oe_ws, idx, wts, pos, y);
}